// Round 4
// baseline (421.369 us; speedup 1.0000x reference)
//
#include <hip/hip_runtime.h>

// ---------------------------------------------------------------------------
// MultiHeadSelfAttention: B=4, L=2048, D=1024, H=16, dh=64.
// R12: GEMMs ported to the 256x256 8-phase counted-vmcnt template (T3+T4,
// m198-equivalent: linear LDS, no T2 swizzle yet). BK=64, 8 waves (2Mx4N),
// 128 KiB LDS double buffer, vmcnt(4) at phases 4/8 only, raw s_barrier,
// lgkmcnt(0)+sched_barrier(0) per phase (rule #18), setprio around MFMA.
// Stage schedule (iter i computes tiles 2i (buf0) / 2i+1 (buf1)):
//   ph1: A0(2i+1)->buf1   ph2: A1(2i+1)->buf1
//   ph3: B0(2i+2)->buf0   ph4: B1(2i+2)->buf0  [vmcnt(4)]
//   ph5: A0(2i+2)->buf0   ph6: A1(2i+2)->buf0
//   ph7: B0(2i+3)->buf1   ph8: B1(2i+3)->buf1  [vmcnt(4)]
// Every stage targets a region fully read >=1 phase earlier; every read is
// covered by the preceding counted vmcnt + barrier. Tail stages wrap (&15):
// garbage lands only in consumed regions. attn/cvt unchanged from R11.
// ---------------------------------------------------------------------------

typedef __attribute__((ext_vector_type(8))) short short8;   // 8 bf16 = 4 VGPR
typedef __attribute__((ext_vector_type(4))) float f32x4;
typedef __attribute__((ext_vector_type(4))) float floatx4;
typedef __attribute__((ext_vector_type(4))) int int4v;
typedef __attribute__((ext_vector_type(2))) unsigned int u32x2;

#define MFMA16(a, b, c) __builtin_amdgcn_mfma_f32_16x16x32_bf16((a), (b), (c), 0, 0, 0)

__device__ __forceinline__ short f2bf(float f) {
    unsigned u = __float_as_uint(f);
    u += 0x7FFF + ((u >> 16) & 1);   // round-to-nearest-even
    return (short)(u >> 16);
}

// async global -> LDS, 16 B per lane (global_load_lds_dwordx4).
__device__ __forceinline__ void gload_lds16(const short* g, short* l) {
    __builtin_amdgcn_global_load_lds(
        (const __attribute__((address_space(1))) void*)g,
        (__attribute__((address_space(3))) void*)l, 16, 0, 0);
}

// ---------------------------------------------------------------------------
// fp32 -> bf16 bulk converts.
// ---------------------------------------------------------------------------
__device__ __forceinline__ void cvt8(const float* __restrict__ src,
                                     short* __restrict__ dst, int i) {
    const f32x4* p = (const f32x4*)src + (size_t)i * 2;
    const f32x4 u0 = p[0];
    const f32x4 u1 = p[1];
    short8 s;
    s[0] = f2bf(u0[0]); s[1] = f2bf(u0[1]); s[2] = f2bf(u0[2]); s[3] = f2bf(u0[3]);
    s[4] = f2bf(u1[0]); s[5] = f2bf(u1[1]); s[6] = f2bf(u1[2]); s[7] = f2bf(u1[3]);
    ((short8*)dst)[i] = s;
}

__global__ __launch_bounds__(256) void cvt_kernel(
    const float* __restrict__ src, short* __restrict__ dst, int n8)
{
    const int i = blockIdx.x * 256 + threadIdx.x;
    if (i >= n8) return;
    cvt8(src, dst, i);
}

__global__ __launch_bounds__(256) void cvt3_kernel(
    const float* __restrict__ s0, const float* __restrict__ s1,
    const float* __restrict__ s2, short* __restrict__ d0,
    short* __restrict__ d1, short* __restrict__ d2)
{
    const int which = blockIdx.x >> 9;
    const int i = (blockIdx.x & 511) * 256 + threadIdx.x;
    const float* s = which == 0 ? s0 : which == 1 ? s1 : s2;
    short* d = which == 0 ? d0 : which == 1 ? d1 : d2;
    cvt8(s, d, i);
}

__global__ __launch_bounds__(256) void cvt2_kernel(
    const float* __restrict__ s0, short* __restrict__ d0,
    const float* __restrict__ s1, short* __restrict__ d1)
{
    if (blockIdx.x < 4096) {
        cvt8(s0, d0, blockIdx.x * 256 + threadIdx.x);
    } else {
        cvt8(s1, d1, (blockIdx.x - 4096) * 256 + threadIdx.x);
    }
}

// ---------------------------------------------------------------------------
// 256x256 8-phase GEMM body. out = A(8192 x 1024) * W^T + bias, bf16 in.
// 512 threads = 8 waves, wave (wr,wc) owns a 128x64 output sub-tile.
// LDS (shorts): buf p at p*32768: A [256][64] at +0, B [256][64] at +16384.
// K = 1024 = 16 tiles of BK=64 = 8 iters x 2 tiles.
// layout 0/1 -> bf16 (B,H,L,dh); 2 -> bf16 (B,H,dh,L); 3 -> fp32 (M,1024).
// ---------------------------------------------------------------------------
__device__ __forceinline__ void gemm256_body(
    const short* __restrict__ A, const short* __restrict__ W,
    const float* __restrict__ bias, void* __restrict__ out,
    int layout, int m0, int n0, short* lds)
{
    const int t = threadIdx.x;            // 0..511
    const int wave = t >> 6, lane = t & 63;
    const int wr = wave >> 2, wc = wave & 3;
    const int l15 = lane & 15, quad = lane >> 4;

    // staging: thread t covers row t>>3 (0..63) of a 64-row load-slab,
    // col chunk (t&7)*8. Load j of half h = rows h*128 + j*64 .. +63.
    const int grow = t >> 3;
    const int gcol = (t & 7) * 8;
    const short* gA = A + (size_t)(m0 + grow) * 1024 + gcol;
    const short* gB = W + (size_t)(n0 + grow) * 1024 + gcol;
    short* ldst = lds + t * 8;            // t*16 bytes, lane-linear

    // fragment read bases (shorts)
    const int arow = (wr * 128 + l15) * 64 + quad * 8;
    const int brow = 16384 + (wc * 64 + l15) * 64 + quad * 8;

    f32x4 acc[8][4];
#pragma unroll
    for (int i = 0; i < 8; i++)
#pragma unroll
        for (int j = 0; j < 4; j++) {
            acc[i][j][0] = 0.f; acc[i][j][1] = 0.f;
            acc[i][j][2] = 0.f; acc[i][j][3] = 0.f;
        }

#define STAGE(T, h, isA, p) do {                                              \
    const short* g_ = ((isA) ? gA : gB) + (size_t)((h) * 128) * 1024          \
                      + (size_t)(T) * 64;                                     \
    short* l_ = ldst + (p) * 32768 + ((isA) ? 0 : 16384) + (h) * 8192;        \
    gload_lds16(g_, l_);                                                      \
    gload_lds16(g_ + 64 * 1024, l_ + 4096);                                   \
} while (0)

    short8 bf[4][2];

#define PHASE(p, q, T_st, h_st, isA_st, p_st, do_vm) do {                     \
    short8 af[2][2];                                                          \
    _Pragma("unroll")                                                         \
    for (int j = 0; j < 2; j++)                                               \
        _Pragma("unroll")                                                     \
        for (int ks = 0; ks < 2; ks++)                                        \
            af[j][ks] = *(const short8*)                                      \
                &lds[(p) * 32768 + arow + ((q) * 2 + j) * 1024 + ks * 32];    \
    if ((q) == 0) {                                                           \
        _Pragma("unroll")                                                     \
        for (int ni = 0; ni < 4; ni++)                                        \
            _Pragma("unroll")                                                 \
            for (int ks = 0; ks < 2; ks++)                                    \
                bf[ni][ks] = *(const short8*)                                 \
                    &lds[(p) * 32768 + brow + ni * 1024 + ks * 32];           \
    }                                                                         \
    STAGE(T_st, h_st, isA_st, p_st);                                          \
    if (do_vm) asm volatile("s_waitcnt vmcnt(4)");                            \
    __builtin_amdgcn_s_barrier();                                             \
    asm volatile("s_waitcnt lgkmcnt(0)");                                     \
    __builtin_amdgcn_sched_barrier(0);                                        \
    __builtin_amdgcn_s_setprio(1);                                            \
    _Pragma("unroll")                                                         \
    for (int j = 0; j < 2; j++)                                               \
        _Pragma("unroll")                                                     \
        for (int ni = 0; ni < 4; ni++) {                                      \
            acc[(q) * 2 + j][ni] =                                            \
                MFMA16(af[j][0], bf[ni][0], acc[(q) * 2 + j][ni]);            \
            acc[(q) * 2 + j][ni] =                                            \
                MFMA16(af[j][1], bf[ni][1], acc[(q) * 2 + j][ni]);            \
        }                                                                     \
    __builtin_amdgcn_s_setprio(0);                                            \
    __builtin_amdgcn_s_barrier();                                             \
} while (0)

    // Prologue: tile0 B+A -> buf0, tile1 B -> buf1 (12 loads); leave tile1's
    // B (4 loads) in flight.
    STAGE(0, 0, false, 0); STAGE(0, 1, false, 0);
    STAGE(0, 0, true,  0); STAGE(0, 1, true,  0);
    STAGE(1, 0, false, 1); STAGE(1, 1, false, 1);
    asm volatile("s_waitcnt vmcnt(4)");
    __builtin_amdgcn_s_barrier();

    for (int i = 0; i < 8; i++) {
        const int t1 = 2 * i + 1;
        const int n2 = (2 * i + 2) & 15;   // wraps harmlessly on last iter
        const int n3 = (2 * i + 3) & 15;
        // phases 1-4: compute tile 2i from buf0
        PHASE(0, 0, t1, 0, true,  1, false);
        PHASE(0, 1, t1, 1, true,  1, false);
        PHASE(0, 2, n2, 0, false, 0, false);
        PHASE(0, 3, n2, 1, false, 0, true);
        // phases 5-8: compute tile 2i+1 from buf1
        PHASE(1, 0, n2, 0, true,  0, false);
        PHASE(1, 1, n2, 1, true,  0, false);
        PHASE(1, 2, n3, 0, false, 1, false);
        PHASE(1, 3, n3, 1, false, 1, true);
    }
#undef PHASE
#undef STAGE

    // Epilogue. C layout: col = lane&15 (-> n), row = quad*4 + r (-> m).
#pragma unroll
    for (int ni = 0; ni < 4; ni++) {
        const int gn = n0 + wc * 64 + ni * 16 + l15;
        const float bv = bias[gn];
#pragma unroll
        for (int mi = 0; mi < 8; mi++) {
#pragma unroll
            for (int r = 0; r < 4; r++) {
                const int gm = m0 + wr * 128 + mi * 16 + quad * 4 + r;
                const float v = acc[mi][ni][r] + bv;
                if (layout == 3) {
                    ((float*)out)[(size_t)gm * 1024 + gn] = v;
                } else {
                    const int b = gm >> 11, l = gm & 2047;  // L = 2048
                    const int h = gn >> 6,  d = gn & 63;    // dh = 64
                    size_t idx;
                    if (layout == 2)
                        idx = ((size_t)(b * 16 + h) * 64 + d) * 2048 + l;
                    else
                        idx = ((size_t)(b * 16 + h) * 2048 + l) * 64 + d;
                    ((short*)out)[idx] = f2bf(v);
                }
            }
        }
    }
}

// fused QKV: grid (32, 12); panel = by>>2 selects {Q,K,V}; XCD-chunked swizzle.
__global__ __launch_bounds__(512, 2) void qkv_kernel(
    const short* __restrict__ Xb,
    const short* __restrict__ Wq, const short* __restrict__ Wk,
    const short* __restrict__ Wv,
    const float* __restrict__ bq, const float* __restrict__ bk,
    const float* __restrict__ bv,
    short* __restrict__ Qo, short* __restrict__ Ko, short* __restrict__ Vo)
{
    extern __shared__ short lds[];
    const int id = blockIdx.y * 32 + blockIdx.x;        // 0..383
    const int nid = (id & 7) * 48 + (id >> 3);          // bijective (384%8==0)
    const int bx = nid & 31, by = nid >> 5;
    const int chunk = by >> 2;                          // 0=Q,1=K,2=V
    const int n0 = (by & 3) * 256;
    const short* W = chunk == 0 ? Wq : chunk == 1 ? Wk : Wv;
    const float* bs = chunk == 0 ? bq : chunk == 1 ? bk : bv;
    void* out = chunk == 0 ? (void*)Qo : chunk == 1 ? (void*)Ko : (void*)Vo;
    gemm256_body(Xb, W, bs, out, chunk, bx * 256, n0, lds);
}

__global__ __launch_bounds__(512, 2) void gemm_kernel(
    const short* __restrict__ A, const short* __restrict__ W,
    const float* __restrict__ bias, void* __restrict__ out, int layout)
{
    extern __shared__ short lds[];
    const int id = blockIdx.y * 32 + blockIdx.x;        // 0..127
    const int nid = (id & 7) * 16 + (id >> 3);          // bijective (128%8==0)
    const int bx = nid & 31, by = nid >> 5;
    gemm256_body(A, W, bias, out, layout, bx * 256, by * 256, lds);
}

// ---------------------------------------------------------------------------
// Attention (unchanged from R10/R11).
// ---------------------------------------------------------------------------
__global__ __launch_bounds__(256, 2) void attn_kernel(
    const short* __restrict__ Q, const short* __restrict__ Kc,
    const short* __restrict__ VT, const int* __restrict__ mask,
    float* __restrict__ O)
{
    __shared__ short Plds_all[4][4][16 * 72];   // 36864 B

    const int blk = blockIdx.x;          // 512 blocks
    const int bh = blk & 63;             // same bh -> same XCD
    const int qg = blk >> 6;             // 0..7 (256 rows each)
    const int b = bh >> 4, h = bh & 15;
    const int t = threadIdx.x;
    const int wave = t >> 6, lane = t & 63;
    const int l15 = lane & 15, quad = lane >> 4;

    const short* Qb = Q  + (size_t)bh * 2048 * 64;
    const short* Kb = Kc + (size_t)bh * 2048 * 64;
    const short* Vb = VT + (size_t)bh * 64 * 2048;
    const int* mrow = mask + b * 2048;

    const float SC = 0.125f * 1.44269504f;

    const int qbase = qg * 256 + wave * 64;

    short8 aq[4][2];
#pragma unroll
    for (int tt = 0; tt < 4; tt++) {
        const short* qp = Qb + (size_t)(qbase + tt * 16 + l15) * 64 + quad * 8;
        aq[tt][0] = *(const short8*)(qp);
        aq[tt][1] = *(const short8*)(qp + 32);
    }

    short8 vone;
#pragma unroll
    for (int j = 0; j < 8; j++) vone[j] = (short)0x3F80;

    floatx4 accO[4][5];
#pragma unroll
    for (int tt = 0; tt < 4; tt++)
#pragma unroll
        for (int ni = 0; ni < 5; ni++) {
            accO[tt][ni][0] = 0.f; accO[tt][ni][1] = 0.f;
            accO[tt][ni][2] = 0.f; accO[tt][ni][3] = 0.f;
        }

    for (int c0 = 0; c0 < 2048; c0 += 64) {
        short8 kreg[4][2];
#pragma unroll
        for (int g = 0; g < 4; g++) {
            const short* kp = Kb + (size_t)(c0 + g * 16 + l15) * 64 + quad * 8;
            kreg[g][0] = *(const short8*)(kp);
            kreg[g][1] = *(const short8*)(kp + 32);
        }
        f32x4 bias[4];
#pragma unroll
        for (int g = 0; g < 4; g++) {
            const int4v mv = *(const int4v*)&mrow[c0 + g * 16 + quad * 4];
#pragma unroll
            for (int r = 0; r < 4; r++) bias[g][r] = mv[r] ? -1e9f : 0.f;
        }
        short8 vreg[4][2];
#pragma unroll
        for (int ni = 0; ni < 4; ni++) {
            const short* vp = Vb + (size_t)(ni * 16 + l15) * 2048 + c0 + quad * 8;
            vreg[ni][0] = *(const short8*)(vp);
            vreg[ni][1] = *(const short8*)(vp + 32);
        }

#pragma unroll
        for (int tt = 0; tt < 4; tt++) {
            floatx4 s[4];
            __builtin_amdgcn_s_setprio(1);
#pragma unroll
            for (int g = 0; g < 4; g++) {
                floatx4 z = bias[g];
                z = MFMA16(kreg[g][0], aq[tt][0], z);
                s[g] = MFMA16(kreg[g][1], aq[tt][1], z);
            }
            __builtin_amdgcn_s_setprio(0);
            short* Pl = &Plds_all[wave][tt][0];
#pragma unroll
            for (int g = 0; g < 4; g++) {
                const float p0 = exp2f(s[g][0] * SC);
                const float p1 = exp2f(s[g][1] * SC);
                const float p2 = exp2f(s[g][2] * SC);
                const float p3 = exp2f(s[g][3] * SC);
                unsigned lo, hi;
                asm("v_cvt_pk_bf16_f32 %0, %1, %2" : "=v"(lo) : "v"(p0), "v"(p1));
                asm("v_cvt_pk_bf16_f32 %0, %1, %2" : "=v"(hi) : "v"(p2), "v"(p3));
                u32x2 w; w[0] = lo; w[1] = hi;
                *(u32x2*)&Pl[l15 * 72 + g * 16 + quad * 4] = w;
            }
        }

        asm volatile("s_waitcnt lgkmcnt(0)" ::: "memory");

#pragma unroll
        for (int tt = 0; tt < 4; tt++) {
            const short* Pl = &Plds_all[wave][tt][0];
            const short8 pa0 = *(const short8*)&Pl[l15 * 72 + quad * 8];
            const short8 pa1 = *(const short8*)&Pl[l15 * 72 + 32 + quad * 8];
            __builtin_amdgcn_s_setprio(1);
#pragma unroll
            for (int ni = 0; ni < 4; ni++) {
                accO[tt][ni] = MFMA16(pa0, vreg[ni][0], accO[tt][ni]);
                accO[tt][ni] = MFMA16(pa1, vreg[ni][1], accO[tt][ni]);
            }
            accO[tt][4] = MFMA16(pa0, vone, accO[tt][4]);
            accO[tt][4] = MFMA16(pa1, vone, accO[tt][4]);
            __builtin_amdgcn_s_setprio(0);
        }
    }

#pragma unroll
    for (int tt = 0; tt < 4; tt++) {
#pragma unroll
        for (int r = 0; r < 4; r++) {
            const float inv = 1.0f / fmaxf(accO[tt][4][r], 1e-30f);
            const int l = qbase + tt * 16 + quad * 4 + r;
#pragma unroll
            for (int ni = 0; ni < 4; ni++) {
                O[(size_t)(b * 2048 + l) * 1024 + h * 64 + ni * 16 + l15] =
                    accO[tt][ni][r] * inv;
            }
        }
    }
}

// ---------------------------------------------------------------------------
extern "C" void kernel_launch(void* const* d_in, const int* in_sizes, int n_in,
                              void* d_out, int out_size, void* d_ws, size_t ws_size,
                              hipStream_t stream)
{
    const float* x    = (const float*)d_in[0];
    const int*   mask = (const int*)d_in[1];
    const float* wq   = (const float*)d_in[2];
    const float* bq   = (const float*)d_in[3];
    const float* wk   = (const float*)d_in[4];
    const float* bk   = (const float*)d_in[5];
    const float* wv   = (const float*)d_in[6];
    const float* bv   = (const float*)d_in[7];
    const float* wo   = (const float*)d_in[8];
    const float* bo   = (const float*)d_in[9];
    float* out = (float*)d_out;

    // allow 128 KiB dynamic LDS (once per process; not stream-ordered).
    static bool lds_init = false;
    if (!lds_init) {
        (void)hipFuncSetAttribute((const void*)qkv_kernel,
            hipFuncAttributeMaxDynamicSharedMemorySize, 131072);
        (void)hipFuncSetAttribute((const void*)gemm_kernel,
            hipFuncAttributeMaxDynamicSharedMemorySize, 131072);
        lds_init = true;
    }

    // ws (48 MiB): [Qbuf bf16 16MB][Kbuf bf16 16MB][Vt bf16 16MB]
    short* Qbuf = (short*)d_ws;
    short* Kbuf = Qbuf + (size_t)8 * 1024 * 1024;
    short* Vt   = Kbuf + (size_t)8 * 1024 * 1024;

    // d_out doubles as scratch until attn writes it.
    short* Xb  = (short*)d_out;
    short* Wqb = Xb  + (size_t)8 * 1024 * 1024;
    short* Wkb = Wqb + (size_t)1024 * 1024;
    short* Wvb = Wkb + (size_t)1024 * 1024;

    dim3 block(256);

    cvt_kernel<<<dim3(4096), block, 0, stream>>>(x, Xb, 1024 * 1024);
    cvt3_kernel<<<dim3(1536), block, 0, stream>>>(wq, wk, wv, Wqb, Wkb, Wvb);

    qkv_kernel<<<dim3(32, 12), dim3(512), 131072, stream>>>(
        Xb, Wqb, Wkb, Wvb, bq, bk, bv, Qbuf, Kbuf, Vt);

    attn_kernel<<<dim3(512), block, 0, stream>>>(Qbuf, Kbuf, Vt, mask, out);

    short* Ob  = Qbuf;
    short* Wob = Kbuf;
    cvt2_kernel<<<dim3(4608), block, 0, stream>>>(out, Ob, wo, Wob);

    gemm_kernel<<<dim3(32, 4), dim3(512), 131072, stream>>>(Ob, Wob, bo, out, 3);
}

// Round 5
// 354.279 us; speedup vs baseline: 1.1894x; 1.1894x over previous
//
#include <hip/hip_runtime.h>

// ---------------------------------------------------------------------------
// MultiHeadSelfAttention: B=4, L=2048, D=1024, H=16, dh=64.
// R13: GEMM phase reverted to R11 (m97 structure, 3 blocks/CU — the R12
// 8-phase port regressed at this shape: 1 block/CU + half-empty grid rounds).
// attn: (1) exp2 via raw v_exp_f32 (__builtin_amdgcn_exp2f) instead of the
// precise OCML exp2f path; (2) softmax scale folded into Q at the QKV
// epilogue (oscale param) — removes 64 v_mul per iter.
// ---------------------------------------------------------------------------

typedef __attribute__((ext_vector_type(8))) short short8;   // 8 bf16 = 4 VGPR
typedef __attribute__((ext_vector_type(4))) float f32x4;
typedef __attribute__((ext_vector_type(4))) float floatx4;
typedef __attribute__((ext_vector_type(4))) int int4v;
typedef __attribute__((ext_vector_type(2))) unsigned int u32x2;

#define MFMA16(a, b, c) __builtin_amdgcn_mfma_f32_16x16x32_bf16((a), (b), (c), 0, 0, 0)

__device__ __forceinline__ short f2bf(float f) {
    unsigned u = __float_as_uint(f);
    u += 0x7FFF + ((u >> 16) & 1);   // round-to-nearest-even
    return (short)(u >> 16);
}

__device__ __forceinline__ float fast_exp2(float x) {
#if __has_builtin(__builtin_amdgcn_exp2f)
    return __builtin_amdgcn_exp2f(x);   // single v_exp_f32
#else
    return exp2f(x);
#endif
}

// async global -> LDS, 16 B per lane (global_load_lds_dwordx4).
__device__ __forceinline__ void gload_lds16(const short* g, short* l) {
    __builtin_amdgcn_global_load_lds(
        (const __attribute__((address_space(1))) void*)g,
        (__attribute__((address_space(3))) void*)l, 16, 0, 0);
}

// ---------------------------------------------------------------------------
// fp32 -> bf16 bulk converts.
// ---------------------------------------------------------------------------
__device__ __forceinline__ void cvt8(const float* __restrict__ src,
                                     short* __restrict__ dst, int i) {
    const f32x4* p = (const f32x4*)src + (size_t)i * 2;
    const f32x4 u0 = p[0];
    const f32x4 u1 = p[1];
    short8 s;
    s[0] = f2bf(u0[0]); s[1] = f2bf(u0[1]); s[2] = f2bf(u0[2]); s[3] = f2bf(u0[3]);
    s[4] = f2bf(u1[0]); s[5] = f2bf(u1[1]); s[6] = f2bf(u1[2]); s[7] = f2bf(u1[3]);
    ((short8*)dst)[i] = s;
}

__global__ __launch_bounds__(256) void cvt_kernel(
    const float* __restrict__ src, short* __restrict__ dst, int n8)
{
    const int i = blockIdx.x * 256 + threadIdx.x;
    if (i >= n8) return;
    cvt8(src, dst, i);
}

__global__ __launch_bounds__(256) void cvt3_kernel(
    const float* __restrict__ s0, const float* __restrict__ s1,
    const float* __restrict__ s2, short* __restrict__ d0,
    short* __restrict__ d1, short* __restrict__ d2)
{
    const int which = blockIdx.x >> 9;
    const int i = (blockIdx.x & 511) * 256 + threadIdx.x;
    const float* s = which == 0 ? s0 : which == 1 ? s1 : s2;
    short* d = which == 0 ? d0 : which == 1 ? d1 : d2;
    cvt8(s, d, i);
}

__global__ __launch_bounds__(256) void cvt2_kernel(
    const float* __restrict__ s0, short* __restrict__ d0,
    const float* __restrict__ s1, short* __restrict__ d1)
{
    if (blockIdx.x < 4096) {
        cvt8(s0, d0, blockIdx.x * 256 + threadIdx.x);
    } else {
        cvt8(s1, d1, (blockIdx.x - 4096) * 256 + threadIdx.x);
    }
}

// ---------------------------------------------------------------------------
// GEMM body (m97 structure): out = A(8192 x 1024) * W^T + bias, bf16 in.
// 128x128 block tile, 4 waves each 64x64, BK=32. Staging via
// global_load_lds width 16 into linear LDS [128][32]. 2 barriers per K-step.
// layout 0/1 -> bf16 (B,H,L,dh); 2 -> bf16 (B,H,dh,L); 3 -> fp32 (M,1024).
// oscale multiplies (acc+bias) before store (used to fold the softmax scale
// into Q; 1.0 elsewhere).
// ---------------------------------------------------------------------------
__device__ __forceinline__ void gemm_body(
    const short* __restrict__ A, const short* __restrict__ W,
    const float* __restrict__ bias, void* __restrict__ out,
    int layout, int m0, int n0, float oscale)
{
    __shared__ short As[128 * 32];
    __shared__ short Bs[128 * 32];

    const int t = threadIdx.x;
    const int wave = t >> 6, lane = t & 63;
    const int wm = (wave >> 1) * 64, wn = (wave & 1) * 64;
    const int l15 = lane & 15, quad = lane >> 4;

    const int r4 = lane >> 2;           // 0..15
    const int kc = (lane & 3) * 8;      // 0,8,16,24

    short* lA0 = &As[wave * 512 + lane * 8];
    short* lA1 = &As[2048 + wave * 512 + lane * 8];
    short* lB0 = &Bs[wave * 512 + lane * 8];
    short* lB1 = &Bs[2048 + wave * 512 + lane * 8];

    const short* gA0 = A + (size_t)(m0 + wave * 16 + r4) * 1024 + kc;
    const short* gA1 = gA0 + (size_t)64 * 1024;
    const short* gB0 = W + (size_t)(n0 + wave * 16 + r4) * 1024 + kc;
    const short* gB1 = gB0 + (size_t)64 * 1024;

    floatx4 acc[4][4];
#pragma unroll
    for (int i = 0; i < 4; i++)
#pragma unroll
        for (int j = 0; j < 4; j++) {
            acc[i][j][0] = 0.f; acc[i][j][1] = 0.f;
            acc[i][j][2] = 0.f; acc[i][j][3] = 0.f;
        }

    for (int kb = 0; kb < 1024; kb += 32) {
        gload_lds16(gA0 + kb, lA0);
        gload_lds16(gA1 + kb, lA1);
        gload_lds16(gB0 + kb, lB0);
        gload_lds16(gB1 + kb, lB1);
        __syncthreads();   // vmcnt(0) drain + barrier: LDS tile ready

        short8 af[4], bfr[4];
#pragma unroll
        for (int mi = 0; mi < 4; mi++)
            af[mi] = *(short8*)&As[(wm + mi * 16 + l15) * 32 + quad * 8];
#pragma unroll
        for (int ni = 0; ni < 4; ni++)
            bfr[ni] = *(short8*)&Bs[(wn + ni * 16 + l15) * 32 + quad * 8];
#pragma unroll
        for (int mi = 0; mi < 4; mi++)
#pragma unroll
            for (int ni = 0; ni < 4; ni++)
                acc[mi][ni] = MFMA16(af[mi], bfr[ni], acc[mi][ni]);

        __syncthreads();   // protect LDS from next K-step's staging
    }

    // Epilogue. C layout: col = lane&15, row = quad*4 + r.
#pragma unroll
    for (int ni = 0; ni < 4; ni++) {
        const int gn = n0 + wn + ni * 16 + l15;
        const float bv = bias[gn];
#pragma unroll
        for (int mi = 0; mi < 4; mi++) {
#pragma unroll
            for (int r = 0; r < 4; r++) {
                const int gm = m0 + wm + mi * 16 + quad * 4 + r;
                const float v = (acc[mi][ni][r] + bv) * oscale;
                if (layout == 3) {
                    ((float*)out)[(size_t)gm * 1024 + gn] = v;
                } else {
                    const int b = gm >> 11, l = gm & 2047;  // L = 2048
                    const int h = gn >> 6,  d = gn & 63;    // dh = 64
                    size_t idx;
                    if (layout == 2)
                        idx = ((size_t)(b * 16 + h) * 64 + d) * 2048 + l;
                    else
                        idx = ((size_t)(b * 16 + h) * 2048 + l) * 64 + d;
                    ((short*)out)[idx] = f2bf(v);
                }
            }
        }
    }
}

// fused QKV: grid (64, 24); blockIdx.y>>3 selects {Q,K,V} panel.
// Q panel is pre-scaled by SC = 0.125 * log2(e) (softmax scale folded in).
__global__ __launch_bounds__(256, 3) void qkv_kernel(
    const short* __restrict__ Xb,
    const short* __restrict__ Wq, const short* __restrict__ Wk,
    const short* __restrict__ Wv,
    const float* __restrict__ bq, const float* __restrict__ bk,
    const float* __restrict__ bv,
    short* __restrict__ Qo, short* __restrict__ Ko, short* __restrict__ Vo)
{
    const int chunk = blockIdx.y >> 3;            // 0=Q,1=K,2=V
    const int n0 = (blockIdx.y & 7) * 128;
    const short* W = chunk == 0 ? Wq : chunk == 1 ? Wk : Wv;
    const float* bs = chunk == 0 ? bq : chunk == 1 ? bk : bv;
    void* out = chunk == 0 ? (void*)Qo : chunk == 1 ? (void*)Ko : (void*)Vo;
    const float os = chunk == 0 ? 0.125f * 1.44269504f : 1.0f;
    gemm_body(Xb, W, bs, out, chunk, blockIdx.x * 128, n0, os);
}

__global__ __launch_bounds__(256, 3) void gemm_kernel(
    const short* __restrict__ A, const short* __restrict__ W,
    const float* __restrict__ bias, void* __restrict__ out, int layout)
{
    gemm_body(A, W, bias, out, layout, blockIdx.x * 128, blockIdx.y * 128, 1.0f);
}

// ---------------------------------------------------------------------------
// Attention. Q arrives pre-scaled by SC, so P = exp2(S + maskbias) directly.
// Swapped QK^T (mfma(K,Q)); P^T packed via v_cvt_pk_bf16_f32 -> ds_write_b64;
// mask as -1e9 accumulator seed; row sums via ones-column MFMA.
// Q,K bf16 (B,H,L,dh); VT bf16 (B,H,dh,L); mask int32; O fp32 (B,L,D).
// ---------------------------------------------------------------------------
__global__ __launch_bounds__(256, 2) void attn_kernel(
    const short* __restrict__ Q, const short* __restrict__ Kc,
    const short* __restrict__ VT, const int* __restrict__ mask,
    float* __restrict__ O)
{
    __shared__ short Plds_all[4][4][16 * 72];   // 36864 B

    const int blk = blockIdx.x;          // 512 blocks
    const int bh = blk & 63;             // same bh -> same XCD
    const int qg = blk >> 6;             // 0..7 (256 rows each)
    const int b = bh >> 4, h = bh & 15;
    const int t = threadIdx.x;
    const int wave = t >> 6, lane = t & 63;
    const int l15 = lane & 15, quad = lane >> 4;

    const short* Qb = Q  + (size_t)bh * 2048 * 64;
    const short* Kb = Kc + (size_t)bh * 2048 * 64;
    const short* Vb = VT + (size_t)bh * 64 * 2048;
    const int* mrow = mask + b * 2048;

    const int qbase = qg * 256 + wave * 64;

    short8 aq[4][2];
#pragma unroll
    for (int tt = 0; tt < 4; tt++) {
        const short* qp = Qb + (size_t)(qbase + tt * 16 + l15) * 64 + quad * 8;
        aq[tt][0] = *(const short8*)(qp);
        aq[tt][1] = *(const short8*)(qp + 32);
    }

    short8 vone;
#pragma unroll
    for (int j = 0; j < 8; j++) vone[j] = (short)0x3F80;

    floatx4 accO[4][5];
#pragma unroll
    for (int tt = 0; tt < 4; tt++)
#pragma unroll
        for (int ni = 0; ni < 5; ni++) {
            accO[tt][ni][0] = 0.f; accO[tt][ni][1] = 0.f;
            accO[tt][ni][2] = 0.f; accO[tt][ni][3] = 0.f;
        }

    for (int c0 = 0; c0 < 2048; c0 += 64) {
        short8 kreg[4][2];
#pragma unroll
        for (int g = 0; g < 4; g++) {
            const short* kp = Kb + (size_t)(c0 + g * 16 + l15) * 64 + quad * 8;
            kreg[g][0] = *(const short8*)(kp);
            kreg[g][1] = *(const short8*)(kp + 32);
        }
        f32x4 bias[4];
#pragma unroll
        for (int g = 0; g < 4; g++) {
            const int4v mv = *(const int4v*)&mrow[c0 + g * 16 + quad * 4];
#pragma unroll
            for (int r = 0; r < 4; r++) bias[g][r] = mv[r] ? -1e9f : 0.f;
        }
        short8 vreg[4][2];
#pragma unroll
        for (int ni = 0; ni < 4; ni++) {
            const short* vp = Vb + (size_t)(ni * 16 + l15) * 2048 + c0 + quad * 8;
            vreg[ni][0] = *(const short8*)(vp);
            vreg[ni][1] = *(const short8*)(vp + 32);
        }

#pragma unroll
        for (int tt = 0; tt < 4; tt++) {
            floatx4 s[4];
            __builtin_amdgcn_s_setprio(1);
#pragma unroll
            for (int g = 0; g < 4; g++) {
                floatx4 z = bias[g];
                z = MFMA16(kreg[g][0], aq[tt][0], z);
                s[g] = MFMA16(kreg[g][1], aq[tt][1], z);
            }
            __builtin_amdgcn_s_setprio(0);
            short* Pl = &Plds_all[wave][tt][0];
#pragma unroll
            for (int g = 0; g < 4; g++) {
                const float p0 = fast_exp2(s[g][0]);
                const float p1 = fast_exp2(s[g][1]);
                const float p2 = fast_exp2(s[g][2]);
                const float p3 = fast_exp2(s[g][3]);
                unsigned lo, hi;
                asm("v_cvt_pk_bf16_f32 %0, %1, %2" : "=v"(lo) : "v"(p0), "v"(p1));
                asm("v_cvt_pk_bf16_f32 %0, %1, %2" : "=v"(hi) : "v"(p2), "v"(p3));
                u32x2 w; w[0] = lo; w[1] = hi;
                *(u32x2*)&Pl[l15 * 72 + g * 16 + quad * 4] = w;
            }
        }

        asm volatile("s_waitcnt lgkmcnt(0)" ::: "memory");

#pragma unroll
        for (int tt = 0; tt < 4; tt++) {
            const short* Pl = &Plds_all[wave][tt][0];
            const short8 pa0 = *(const short8*)&Pl[l15 * 72 + quad * 8];
            const short8 pa1 = *(const short8*)&Pl[l15 * 72 + 32 + quad * 8];
            __builtin_amdgcn_s_setprio(1);
#pragma unroll
            for (int ni = 0; ni < 4; ni++) {
                accO[tt][ni] = MFMA16(pa0, vreg[ni][0], accO[tt][ni]);
                accO[tt][ni] = MFMA16(pa1, vreg[ni][1], accO[tt][ni]);
            }
            accO[tt][4] = MFMA16(pa0, vone, accO[tt][4]);
            accO[tt][4] = MFMA16(pa1, vone, accO[tt][4]);
            __builtin_amdgcn_s_setprio(0);
        }
    }

#pragma unroll
    for (int tt = 0; tt < 4; tt++) {
#pragma unroll
        for (int r = 0; r < 4; r++) {
            const float inv = 1.0f / fmaxf(accO[tt][4][r], 1e-30f);
            const int l = qbase + tt * 16 + quad * 4 + r;
#pragma unroll
            for (int ni = 0; ni < 4; ni++) {
                O[(size_t)(b * 2048 + l) * 1024 + h * 64 + ni * 16 + l15] =
                    accO[tt][ni][r] * inv;
            }
        }
    }
}

// ---------------------------------------------------------------------------
extern "C" void kernel_launch(void* const* d_in, const int* in_sizes, int n_in,
                              void* d_out, int out_size, void* d_ws, size_t ws_size,
                              hipStream_t stream)
{
    const float* x    = (const float*)d_in[0];
    const int*   mask = (const int*)d_in[1];
    const float* wq   = (const float*)d_in[2];
    const float* bq   = (const float*)d_in[3];
    const float* wk   = (const float*)d_in[4];
    const float* bk   = (const float*)d_in[5];
    const float* wv   = (const float*)d_in[6];
    const float* bv   = (const float*)d_in[7];
    const float* wo   = (const float*)d_in[8];
    const float* bo   = (const float*)d_in[9];
    float* out = (float*)d_out;   // fp32 output (8M floats)

    // ws (48 MiB): [Qbuf bf16 16MB][Kbuf bf16 16MB][Vt bf16 16MB]
    short* Qbuf = (short*)d_ws;
    short* Kbuf = Qbuf + (size_t)8 * 1024 * 1024;
    short* Vt   = Kbuf + (size_t)8 * 1024 * 1024;

    // d_out doubles as scratch until attn writes it.
    short* Xb  = (short*)d_out;
    short* Wqb = Xb  + (size_t)8 * 1024 * 1024;
    short* Wkb = Wqb + (size_t)1024 * 1024;
    short* Wvb = Wkb + (size_t)1024 * 1024;

    dim3 block(256);

    cvt_kernel<<<dim3(4096), block, 0, stream>>>(x, Xb, 1024 * 1024);
    cvt3_kernel<<<dim3(1536), block, 0, stream>>>(wq, wk, wv, Wqb, Wkb, Wvb);

    qkv_kernel<<<dim3(64, 24), block, 0, stream>>>(
        Xb, Wqb, Wkb, Wvb, bq, bk, bv, Qbuf, Kbuf, Vt);

    attn_kernel<<<dim3(512), block, 0, stream>>>(Qbuf, Kbuf, Vt, mask, out);

    short* Ob  = Qbuf;
    short* Wob = Kbuf;
    cvt2_kernel<<<dim3(4608), block, 0, stream>>>(out, Ob, wo, Wob);

    gemm_kernel<<<dim3(64, 8), block, 0, stream>>>(Ob, Wob, bo, out, 3);
}